// Round 12
// baseline (51.946 us; speedup 1.0000x reference)
//
#include <hip/hip_runtime.h>
#include <hip/hip_bf16.h>

// ---------------------------------------------------------------------------
// R12: TWO kernels total (testing the ~5us/launch-gap hypothesis; R5-R11 all
// show ~20us unexplained vs bottom-up floors, R7 single-kernel showed +4us).
//   K_A: weight self-stage (LDS, coalesced) + conv+BN+ReLU + proj ->
//        fragment-order prF/pdF/pvF + rgbd partials + counter=0.
//   K_B: single-pass column stats (validated R11 hot loop) + gapPart, then
//        last-block-done (threadfence+atomicAdd ticket) runs the MLP gate
//        with all 512 threads (replaces the latency-bound 4-block k_gate).
// Math (validated R8-R11): gap_att[c]=sum_j W[j,c]/Z[j], W=sum_i p_ij v[i,c],
// Z=sum_i p_ij, p=exp2(e2), v=pr+pd; prF/pdF/pvF stored in MFMA fragment
// order so every hot-loop load is base+lane*{8,16}B coalesced.
// ---------------------------------------------------------------------------

typedef __bf16 bf16;
typedef __bf16 bf16x4 __attribute__((ext_vector_type(4)));
typedef __bf16 bf16x8 __attribute__((ext_vector_type(8)));
typedef float  f32x4  __attribute__((ext_vector_type(4)));
typedef float  float4v __attribute__((ext_vector_type(4)));
typedef short  s4     __attribute__((ext_vector_type(4)));

#define MFMA_BF16(a, b, c) __builtin_amdgcn_mfma_f32_16x16x32_bf16((a), (b), (c), 0, 0, 0)

#if defined(__has_builtin)
# if __has_builtin(__builtin_amdgcn_mfma_f32_16x16x16bf16_1k)
#  define MFMA16_BUILTIN(a, b, c) __builtin_amdgcn_mfma_f32_16x16x16bf16_1k((a), (b), (c), 0, 0, 0)
# elif __has_builtin(__builtin_amdgcn_mfma_f32_16x16x16_bf16)
#  define MFMA16_BUILTIN(a, b, c) __builtin_amdgcn_mfma_f32_16x16x16_bf16((a), (b), (c), 0, 0, 0)
# endif
#endif

__device__ __forceinline__ f32x4 MFMA16(s4 a, s4 b, f32x4 c) {
#ifdef MFMA16_BUILTIN
    return MFMA16_BUILTIN(a, b, c);
#else
    asm("v_mfma_f32_16x16x16_bf16 %0, %1, %2, %0" : "+v"(c) : "v"(a), "v"(b));
    return c;
#endif
}

#if defined(__has_builtin)
# if __has_builtin(__builtin_amdgcn_exp2f)
#  define EXP2(x) __builtin_amdgcn_exp2f(x)
# else
#  define EXP2(x) exp2f(x)
# endif
#else
# define EXP2(x) exp2f(x)
#endif

#define K_E 0.18033688f      // 0.125 * log2(e)

__device__ __forceinline__ int swz128(int row, int colByte) {
    return row * 128 + (colByte ^ ((row & 7) << 4));
}
__device__ __forceinline__ int swz512(int row, int colByte) {
    return row * 512 + (colByte ^ ((row & 15) << 4));
}

// LDS union offsets for K_A (weights phase reuses the tile phase's space)
#define OW_W   0        // ldsW  [64][512B]  conv_w bf16 swz512  (32KB)
#define OW_WR  32768    // ldsWR [64][128B]  rgb_w bf16 swz128   (8KB)
#define OW_WD  40960    // ldsWD [64][128B]  dep_w bf16 swz128   (8KB)
#define OT_C   0        // ldsC  [32][512B]  dep tile            (16KB)
#define OT_R   16384    // ldsR  [32][128B]  rgb tile            (4KB)
#define OT_D   20480    // ldsD  [32][128B]  depf tile           (4KB)
#define O_S1   49152
#define O_B1   49408
#define O_RED  49664    // 8*64*4 = 2KB
#define SMEMA  51712

// ---------------------------------------------------------------------------
// K_A: self-staged weights -> conv+BN+ReLU -> proj -> fragment-order stores.
// 512 blocks XCD-affine x 512 thr (8 waves = 4 ot x 2 ph), 2 blk/CU.
// ---------------------------------------------------------------------------
__global__ __launch_bounds__(512, 2) void k_front(
    const float* __restrict__ rgb, const float* __restrict__ dep,
    const float* __restrict__ conv_w,
    const float* __restrict__ bn1_g, const float* __restrict__ bn1_b,
    const float* __restrict__ bn1_m, const float* __restrict__ bn1_v,
    const float* __restrict__ rgb_w, const float* __restrict__ dep_w,
    bf16* __restrict__ prF, bf16* __restrict__ pdF, bf16* __restrict__ pvF,
    float* __restrict__ rgbdPart, int* __restrict__ counter)
{
    const int bid = blockIdx.x;
    const int xcd = bid & 7;
    const int b    = xcd >> 1;
    const int tile = ((bid >> 3) << 1) | (xcd & 1);   // 0..127
    const int p0   = tile * 32;
    const int tid = threadIdx.x;
    const int w   = tid >> 6;
    const int lane = tid & 63;
    const int l15 = lane & 15;
    const int lg  = lane >> 4;
    const int ot4 = w & 3;
    const int ot  = ot4 * 16;
    const int ph  = w >> 2;

    if (bid == 0 && tid == 0) *counter = 0;   // K_B's ticket (stream-ordered)

    __shared__ __align__(16) unsigned char smem[SMEMA];
    float* s1 = (float*)(smem + O_S1);
    float* b1 = (float*)(smem + O_B1);
    float* red = (float*)(smem + O_RED);

    // ---- phase W: stage all weights coalesced -> swizzled LDS bf16 ----
    {
        unsigned char* ldsW  = smem + OW_W;
        unsigned char* ldsWR = smem + OW_WR;
        unsigned char* ldsWD = smem + OW_WD;
        #pragma unroll
        for (int q = 0; q < 8; ++q) {
            const int idx = (q * 512 + tid) * 4;      // float idx in conv_w
            float4v v = *(const float4v*)(conv_w + idx);
            const int o = idx >> 8, c = idx & 255;
            bf16x4 h;
            #pragma unroll
            for (int j = 0; j < 4; ++j) h[j] = (bf16)v[j];
            *(bf16x4*)(ldsW + swz512(o, c * 2)) = h;
        }
        #pragma unroll
        for (int q = 0; q < 2; ++q) {
            const int idx = (q * 512 + tid) * 4;      // float idx in rgb_w/dep_w
            const int o = idx >> 6, c = idx & 63;
            float4v v = *(const float4v*)(rgb_w + idx);
            bf16x4 h;
            #pragma unroll
            for (int j = 0; j < 4; ++j) h[j] = (bf16)v[j];
            *(bf16x4*)(ldsWR + swz128(o, c * 2)) = h;
            v = *(const float4v*)(dep_w + idx);
            #pragma unroll
            for (int j = 0; j < 4; ++j) h[j] = (bf16)v[j];
            *(bf16x4*)(ldsWD + swz128(o, c * 2)) = h;
        }
        if (tid < 64) {
            float sc = bn1_g[tid] * rsqrtf(bn1_v[tid] + 1e-5f);
            s1[tid] = sc;
            b1[tid] = bn1_b[tid] - bn1_m[tid] * sc;
        }
    }
    __syncthreads();

    // ---- fragments -> registers ----
    bf16x8 aW[8], aR[2], aD[2];
    {
        const unsigned char* ldsW  = smem + OW_W;
        const unsigned char* ldsWR = smem + OW_WR;
        const unsigned char* ldsWD = smem + OW_WD;
        const int row = ot + l15;
        #pragma unroll
        for (int kk = 0; kk < 8; ++kk)
            aW[kk] = *(const bf16x8*)(ldsW + swz512(row, (kk * 32 + lg * 8) * 2));
        #pragma unroll
        for (int kk = 0; kk < 2; ++kk) {
            aR[kk] = *(const bf16x8*)(ldsWR + swz128(row, (kk * 32 + lg * 8) * 2));
            aD[kk] = *(const bf16x8*)(ldsWD + swz128(row, (kk * 32 + lg * 8) * 2));
        }
    }
    __syncthreads();   // weights consumed; reuse smem for tiles

    // ---- phase T: stage dep/rgb tiles coalesced ----
    unsigned char* ldsC = smem + OT_C;
    unsigned char* ldsR = smem + OT_R;
    unsigned char* ldsD = smem + OT_D;
    const float* depb = dep + (size_t)b * 256 * 4096;
    const float* rgbb = rgb + (size_t)b * 64 * 4096;
    {
        const int c0 = tid >> 3, seg = tid & 7;
        #pragma unroll
        for (int r = 0; r < 4; ++r) {
            const int c = r * 64 + c0;
            float4v v = *(const float4v*)(depb + (size_t)c * 4096 + p0 + seg * 4);
            #pragma unroll
            for (int k = 0; k < 4; ++k)
                *(bf16*)(ldsC + swz512(seg * 4 + k, c * 2)) = (bf16)v[k];
        }
        float4v v = *(const float4v*)(rgbb + (size_t)c0 * 4096 + p0 + seg * 4);
        #pragma unroll
        for (int k = 0; k < 4; ++k)
            *(bf16*)(ldsR + swz128(seg * 4 + k, c0 * 2)) = (bf16)v[k];
    }
    __syncthreads();

    // ---- conv MFMA K=256 ----
    const int prow = ph * 16 + l15;
    f32x4 acc = {0.f, 0.f, 0.f, 0.f};
    #pragma unroll
    for (int kk = 0; kk < 8; ++kk) {
        bf16x8 bF = *(const bf16x8*)(ldsC + swz512(prow, (kk * 32 + lg * 8) * 2));
        acc = MFMA_BF16(aW[kk], bF, acc);
    }
    {
        const int o0 = ot + lg * 4;
        bf16x4 v4;
        #pragma unroll
        for (int r = 0; r < 4; ++r) {
            float x = acc[r] * s1[o0 + r] + b1[o0 + r];
            v4[r] = (bf16)(x > 0.f ? x : 0.f);
        }
        *(bf16x4*)(ldsD + swz128(prow, o0 * 2)) = v4;
    }
    __syncthreads();

    // ---- proj GEMMs (K=64) + fragment-order stores ----
    f32x4 accR = {0.f, 0.f, 0.f, 0.f}, accD = {0.f, 0.f, 0.f, 0.f};
    #pragma unroll
    for (int kk = 0; kk < 2; ++kk) {
        const int cb = (kk * 32 + lg * 8) * 2;
        bf16x8 bR = *(const bf16x8*)(ldsR + swz128(prow, cb));
        bf16x8 bD = *(const bf16x8*)(ldsD + swz128(prow, cb));
        accR = MFMA_BF16(aR[kk], bR, accR);
        accD = MFMA_BF16(aD[kk], bD, accD);
    }
    {
        const int o0 = ot + lg * 4;
        const size_t itile = (size_t)tile * 2 + ph;     // i>>4 (batch-local)
        const size_t fbase = (size_t)b * 262144 + itile * 1024;
        const size_t prOff = fbase + (size_t)(o0 >> 3) * 128 + l15 * 8 + (o0 & 7);
        bf16x4 vR, vD;
        #pragma unroll
        for (int r = 0; r < 4; ++r) {
            vR[r] = (bf16)(accR[r] * K_E);
            vD[r] = (bf16)accD[r];
        }
        *(bf16x4*)(prF + prOff) = vR;
        *(bf16x4*)(pdF + prOff) = vD;
        const size_t pvBase = fbase + ot4 * 256 + (l15 >> 2) * 64 + lg * 16 + (l15 & 3);
        #pragma unroll
        for (int r = 0; r < 4; ++r)
            pvF[pvBase + r * 4] = (bf16)(accR[r] + accD[r]);
    }

    // ---- rgbd per-tile sums ----
    {
        const int c = tid & 63, g8 = tid >> 6;
        float sum = 0.f;
        #pragma unroll
        for (int q = 0; q < 4; ++q) {
            const int pp = g8 * 4 + q;
            sum += (float)*(const bf16*)(ldsR + swz128(pp, c * 2))
                 + (float)*(const bf16*)(ldsD + swz128(pp, c * 2));
        }
        red[g8 * 64 + c] = sum;
    }
    __syncthreads();
    if (tid < 64) {
        float s = 0.f;
        #pragma unroll
        for (int g = 0; g < 8; ++g) s += red[g * 64 + tid];
        rgbdPart[((size_t)b * 128 + tile) * 64 + tid] = s;
    }
}

// ---------------------------------------------------------------------------
// K_B: single-pass column stats (R11 hot loop) + last-block-done MLP gate.
// 256 blocks (4b x 64 j-chunks, XCD-affine) x 512 thr.
// ---------------------------------------------------------------------------
__global__ __launch_bounds__(512, 2) void k_col(
    const bf16* __restrict__ prF, const bf16* __restrict__ pdF,
    const bf16* __restrict__ pvF,
    float* __restrict__ gapPart, const float* __restrict__ rgbdPart,
    int* __restrict__ counter,
    const float* __restrict__ mlp1_w,
    const float* __restrict__ bn2_g, const float* __restrict__ bn2_b,
    const float* __restrict__ bn2_m, const float* __restrict__ bn2_v,
    const float* __restrict__ mlp2_w,
    const float* __restrict__ bn3_g, const float* __restrict__ bn3_b,
    const float* __restrict__ bn3_m, const float* __restrict__ bn3_v,
    float* __restrict__ out)
{
    const int bid = blockIdx.x;
    const int xcd = bid & 7, b = xcd >> 1;
    const int jt64 = ((bid >> 3) << 1) | (xcd & 1);   // 0..63
    const int tid = threadIdx.x;
    const int ih = tid >> 6, lane = tid & 63;
    const int l15 = lane & 15, lg = lane >> 4;

    __shared__ float zred[8][64];
    __shared__ float zfull[64];
    __shared__ float gred[8][64];
    __shared__ float gv4[4][64];
    __shared__ float h4[4][24];
    __shared__ int winflag;
    if (tid == 0) winflag = 0;

    const bf16* prb = prF + (size_t)b * 262144;
    const bf16* pdb = pdF + (size_t)b * 262144;
    const bf16* pvb = pvF + (size_t)b * 262144;

    // resident b-frags for 4 j-subtiles
    bf16x8 B0[4], B1[4];
    #pragma unroll
    for (int jt = 0; jt < 4; ++jt) {
        const bf16* q = pdb + (size_t)(jt64 * 4 + jt) * 1024 + lane * 8;
        B0[jt] = *(const bf16x8*)q;
        B1[jt] = *(const bf16x8*)(q + 512);
    }

    f32x4 acc[4][4];
    #pragma unroll
    for (int jt = 0; jt < 4; ++jt)
        #pragma unroll
        for (int cb = 0; cb < 4; ++cb)
            acc[jt][cb] = (f32x4){0.f, 0.f, 0.f, 0.f};
    float z[4] = {0.f, 0.f, 0.f, 0.f};

    const bf16* pA = prb + (size_t)ih * 32 * 1024;
    const bf16* pV = pvb + (size_t)ih * 32 * 1024;

    bf16x8 a0 = *(const bf16x8*)(pA + lane * 8);
    bf16x8 a1 = *(const bf16x8*)(pA + 512 + lane * 8);
    bf16x4 v0 = *(const bf16x4*)(pV + lane * 4);
    bf16x4 v1 = *(const bf16x4*)(pV + 256 + lane * 4);
    bf16x4 v2 = *(const bf16x4*)(pV + 512 + lane * 4);
    bf16x4 v3 = *(const bf16x4*)(pV + 768 + lane * 4);

    for (int t = 0; t < 32; ++t) {
        const bf16x8 ca0 = a0, ca1 = a1;
        const bf16x4 cv0 = v0, cv1 = v1, cv2 = v2, cv3 = v3;
        if (t < 31) {
            pA += 1024; pV += 1024;
            a0 = *(const bf16x8*)(pA + lane * 8);
            a1 = *(const bf16x8*)(pA + 512 + lane * 8);
            v0 = *(const bf16x4*)(pV + lane * 4);
            v1 = *(const bf16x4*)(pV + 256 + lane * 4);
            v2 = *(const bf16x4*)(pV + 512 + lane * 4);
            v3 = *(const bf16x4*)(pV + 768 + lane * 4);
        }
        #pragma unroll
        for (int jt = 0; jt < 4; ++jt) {
            f32x4 e = {0.f, 0.f, 0.f, 0.f};
            e = MFMA_BF16(ca0, B0[jt], e);
            e = MFMA_BF16(ca1, B1[jt], e);
            bf16x4 ph;
            #pragma unroll
            for (int r = 0; r < 4; ++r) {
                float pf = EXP2(e[r]);
                z[jt] += pf;
                ph[r] = (bf16)pf;
            }
            const s4 pB = __builtin_bit_cast(s4, ph);
            acc[jt][0] = MFMA16(__builtin_bit_cast(s4, cv0), pB, acc[jt][0]);
            acc[jt][1] = MFMA16(__builtin_bit_cast(s4, cv1), pB, acc[jt][1]);
            acc[jt][2] = MFMA16(__builtin_bit_cast(s4, cv2), pB, acc[jt][2]);
            acc[jt][3] = MFMA16(__builtin_bit_cast(s4, cv3), pB, acc[jt][3]);
        }
    }

    // ---- Z reduce ----
    #pragma unroll
    for (int jt = 0; jt < 4; ++jt) {
        float zv = z[jt];
        zv += __shfl_xor(zv, 16);
        zv += __shfl_xor(zv, 32);
        if (lane < 16) zred[ih][jt * 16 + lane] = zv;
    }
    __syncthreads();
    if (tid < 64) {
        float s = 0.f;
        #pragma unroll
        for (int k = 0; k < 8; ++k) s += zred[k][tid];
        zfull[tid] = s;
    }
    __syncthreads();

    // ---- g[c] = sum_jt sum_l15 acc*zinv ----
    float zinv[4];
    #pragma unroll
    for (int jt = 0; jt < 4; ++jt) {
        const float zj = zfull[jt * 16 + l15];
        float zi = __builtin_amdgcn_rcpf(zj);
        zinv[jt] = zi * (2.0f - zj * zi);
    }
    #pragma unroll
    for (int cb = 0; cb < 4; ++cb) {
        #pragma unroll
        for (int r = 0; r < 4; ++r) {
            float v = acc[0][cb][r] * zinv[0] + acc[1][cb][r] * zinv[1]
                    + acc[2][cb][r] * zinv[2] + acc[3][cb][r] * zinv[3];
            v += __shfl_xor(v, 1);
            v += __shfl_xor(v, 2);
            v += __shfl_xor(v, 4);
            v += __shfl_xor(v, 8);
            if (l15 == 0) gred[ih][cb * 16 + lg * 4 + r] = v;
        }
    }
    __syncthreads();
    if (tid < 64) {
        float s = 0.f;
        #pragma unroll
        for (int k = 0; k < 8; ++k) s += gred[k][tid];
        gapPart[((size_t)b * 64 + jt64) * 64 + tid] = s;
        // release: my store above, then fence, then ticket
        __threadfence();
        int old = atomicAdd(counter, 1);
        if (old == 256 * 64 - 1) winflag = 1;
    }
    __syncthreads();

    // ================= last block: MLP gate (512 threads) ==================
    if (winflag) {
        __threadfence();   // acquire side of the ticket chain
        const int wb = ih >> 1, half = ih & 1;
        float acc2 = 0.f;
        const float* gp = gapPart + ((size_t)wb * 64 + half * 32) * 64 + lane;
        #pragma unroll 4
        for (int r = 0; r < 32; ++r) acc2 += gp[r * 64];
        const float* rp = rgbdPart + ((size_t)wb * 128 + half * 64) * 64 + lane;
        #pragma unroll 4
        for (int r = 0; r < 64; ++r) acc2 += rp[r * 64];
        gred[ih][lane] = acc2;
        __syncthreads();
        if (tid < 256) {
            const int b4 = tid >> 6, c = tid & 63;
            gv4[b4][c] = (gred[2 * b4][c] + gred[2 * b4 + 1][c]) * (1.f / 4096.f);
        }
        __syncthreads();
        if (tid < 96) {
            const int b4 = tid / 24, o = tid % 24;
            float a = 0.f;
            #pragma unroll
            for (int cc = 0; cc < 64; ++cc) a += mlp1_w[o * 64 + cc] * gv4[b4][cc];
            float sc = bn2_g[o] * rsqrtf(bn2_v[o] + 1e-5f);
            a = a * sc + bn2_b[o] - bn2_m[o] * sc;
            h4[b4][o] = a > 0.f ? a : 0.f;
        }
        __syncthreads();
        if (tid < 256) {
            const int b4 = tid >> 6, c = tid & 63;
            float u = 0.f;
            #pragma unroll
            for (int o = 0; o < 24; ++o) u += mlp2_w[c * 24 + o] * h4[b4][o];
            float sc = bn3_g[c] * rsqrtf(bn3_v[c] + 1e-5f);
            u = u * sc + bn3_b[c] - bn3_m[c] * sc;
            out[b4 * 64 + c] = 1.f / (1.f + __expf(-u));
        }
    }
}

// ---------------------------------------------------------------------------
extern "C" void kernel_launch(void* const* d_in, const int* in_sizes, int n_in,
                              void* d_out, int out_size, void* d_ws, size_t ws_size,
                              hipStream_t stream)
{
    const float* rgb    = (const float*)d_in[0];
    const float* dep    = (const float*)d_in[1];
    const float* conv_w = (const float*)d_in[2];
    const float* bn1_g  = (const float*)d_in[3];
    const float* bn1_b  = (const float*)d_in[4];
    const float* bn1_m  = (const float*)d_in[5];
    const float* bn1_v  = (const float*)d_in[6];
    const float* rgb_w  = (const float*)d_in[7];
    const float* dep_w  = (const float*)d_in[8];
    const float* mlp1_w = (const float*)d_in[9];
    const float* bn2_g  = (const float*)d_in[10];
    const float* bn2_b  = (const float*)d_in[11];
    const float* bn2_m  = (const float*)d_in[12];
    const float* bn2_v  = (const float*)d_in[13];
    const float* mlp2_w = (const float*)d_in[14];
    const float* bn3_g  = (const float*)d_in[15];
    const float* bn3_b  = (const float*)d_in[16];
    const float* bn3_m  = (const float*)d_in[17];
    const float* bn3_v  = (const float*)d_in[18];

    char* ws = (char*)d_ws;
    bf16*  prF      = (bf16*)(ws);                                  // 2 MB
    bf16*  pdF      = (bf16*)(ws + (2u << 20));                     // 2 MB
    bf16*  pvF      = (bf16*)(ws + (4u << 20));                     // 2 MB
    float* rgbdPart = (float*)(ws + (6u << 20));                    // 128 KB
    float* gapPart  = (float*)(ws + (6u << 20) + (128u << 10));     // 64 KB
    int*   counter  = (int*)  (ws + (6u << 20) + (192u << 10));     // 4 B

    k_front<<<512, 512, 0, stream>>>(rgb, dep, conv_w,
                                     bn1_g, bn1_b, bn1_m, bn1_v,
                                     rgb_w, dep_w,
                                     prF, pdF, pvF, rgbdPart, counter);
    k_col<<<256, 512, 0, stream>>>(prF, pdF, pvF, gapPart, rgbdPart, counter,
                                   mlp1_w, bn2_g, bn2_b, bn2_m, bn2_v,
                                   mlp2_w, bn3_g, bn3_b, bn3_m, bn3_v,
                                   (float*)d_out);
}